// Round 10
// baseline (162.075 us; speedup 1.0000x reference)
//
#include <hip/hip_runtime.h>

// SpMM (COO): out[rows[e], :] += vals[e] * annotations[cols[e], :]
// N=40000 nodes, E=640000 edges, D=128 feats, fp32 in/out.
//
// Round 14: round-13 with the compile fix (nontemporal load needs an
// ext_vector type, not HIP's int4 wrapper class).
//   Stage A (partition): 8 row-range buckets, LDS ranking -> 20k global
//     atomics (not 640k), block-contiguous 16B writes (full combining).
//   Stage B (scatter): group p (blockIdx&7, XCD heuristic) scans ONLY
//     bucket p sequentially (1x read, coalesced) and does the cursor
//     atomic + pairs store against L2-resident slices (320KB cursor,
//     1.28MB pairs per partition). Convert fused behind (proven).
//   Stage C (pull): round-11 exact (proven best, 8-deep, swizzled).
//   Diagnostic: if stage B stays ~45us despite sequential reads and
//   combined stores, the 640k-atomic coherence chain is the wall.

constexpr int N_NODES = 40000;
constexpr int N_EDGES = 640000;
constexpr int D_FEAT  = 128;
constexpr int CAP     = 32;       // slots per row; deg>CAP spills to overflow
constexpr int OVF_CAP = 16384;
constexpr int CSTR    = 16;       // cursor stride (ints): 1 counter per 64B line

constexpr int NXCD      = 8;
constexpr int PART_ROWS = N_NODES / NXCD;          // 5000 rows per partition
constexpr int BUCK_CAP  = 96000;                   // mean 80000, sigma~265
constexpr int OVF2_CAP  = 4096;

constexpr int A_EPT    = 2;                        // edges/thread (partition)
constexpr int A_BLOCKS = N_EDGES / (256 * A_EPT);  // 1250
constexpr int B_GROUP  = 320;                      // blocks per partition group
constexpr int B_BLOCKS = B_GROUP * NXCD;           // 2560
constexpr int CONV_BLOCKS = (N_NODES * D_FEAT / 8) / 256;  // 2500

// ---- workspace layout (bytes) ----
constexpr size_t WS_CURSOR  = 0;          // int[N*CSTR]            = 2,560,000
constexpr size_t WS_OVFCNT  = 2560000;    // int
constexpr size_t WS_GCNT    = 2560064;    // int[8*16]              = 512
constexpr size_t WS_OVF2CNT = 2560576;    // int
constexpr size_t WS_OVF     = 2560640;    // int4[OVF_CAP]          = 262,144
constexpr size_t WS_OVF2    = 2822784;    // int4[OVF2_CAP]         = 65,536
constexpr size_t WS_ANNB    = 2888320;    // bf16[N*D] as uint      = 10,240,000
constexpr size_t WS_ELIST   = 13128320;   // v4i[8*BUCK_CAP]        = 12,288,000
constexpr size_t WS_PAIRS   = 25416320;   // int2[N*CAP]            = 10,240,000
constexpr size_t WS_NEEDED  = 35656320;
constexpr size_t WS_ZERO    = 2560580;    // cursor+ovfcnt+gcnt+ovf2cnt

typedef int      v2i __attribute__((ext_vector_type(2)));
typedef int      v4i __attribute__((ext_vector_type(4)));
typedef float    v2f __attribute__((ext_vector_type(2)));
typedef float    v4f __attribute__((ext_vector_type(4)));
typedef unsigned v4u __attribute__((ext_vector_type(4)));

__device__ __forceinline__ unsigned f2b_rne(float f) {
    unsigned b = __float_as_uint(f);
    return (b + 0x7fffu + ((b >> 16) & 1u)) >> 16;
}

// Stage A: coarse partition into 8 row-range lists.
// LDS histogram -> per-edge local rank; ONE global atomic per (block,bucket);
// block-contiguous 16B writes (L2 write-combining works: chunk is private).
__global__ __launch_bounds__(256) void partition_kernel(
    const int*   __restrict__ rows,
    const int*   __restrict__ cols,
    const float* __restrict__ vals,
    int* __restrict__ gcnt,              // [8*16], 1 counter per 64B line
    v4i* __restrict__ elist,             // [8][BUCK_CAP]
    int* __restrict__ ovf2cnt, v4i* __restrict__ ovf2)
{
    __shared__ int s_cnt[NXCD];
    __shared__ int s_base[NXCD];
    int tid = threadIdx.x;
    if (tid < NXCD) s_cnt[tid] = 0;
    __syncthreads();

    int e0 = blockIdx.x * (256 * A_EPT) + tid;
    int   r[A_EPT], c[A_EPT], rk[A_EPT], b[A_EPT];
    float v[A_EPT];
    #pragma unroll
    for (int i = 0; i < A_EPT; i++) {
        int e = e0 + i * 256;
        r[i] = __builtin_nontemporal_load(rows + e);
        c[i] = __builtin_nontemporal_load(cols + e);
        v[i] = __builtin_nontemporal_load(vals + e);
        b[i] = r[i] / PART_ROWS;
        rk[i] = atomicAdd(&s_cnt[b[i]], 1);
    }
    __syncthreads();
    if (tid < NXCD) s_base[tid] = atomicAdd(&gcnt[tid * CSTR], s_cnt[tid]);
    __syncthreads();

    #pragma unroll
    for (int i = 0; i < A_EPT; i++) {
        int pos = s_base[b[i]] + rk[i];
        v4i e4;
        e4.x = r[i];
        e4.y = c[i];
        e4.z = __float_as_int(v[i]);
        e4.w = 0;
        if (pos < BUCK_CAP) {
            elist[(size_t)b[i] * BUCK_CAP + pos] = e4;   // combined in L2
        } else {
            int o = atomicAdd(ovf2cnt, 1);
            if (o < OVF2_CAP) ovf2[o] = e4;
        }
    }
}

__device__ __forceinline__ void scatter_to_row(
    int r, int c, float v, int* cursor, v2i* pairs,
    int* ovfcnt, v4i* ovf)
{
    int slot = atomicAdd(&cursor[r * CSTR], 1);
    if (slot < CAP) {
        v2i q;
        q.x = c;
        q.y = __float_as_int(v);
        pairs[r * CAP + slot] = q;
    } else {
        int o = atomicAdd(ovfcnt, 1);
        if (o < OVF_CAP) {
            v4i e4;
            e4.x = r; e4.y = c; e4.z = __float_as_int(v); e4.w = 0;
            ovf[o] = e4;
        }
    }
}

// Stage B: XCD-local scatter (group p scans bucket p sequentially) + convert.
__global__ __launch_bounds__(256) void build_kernel(
    const float* __restrict__ ann,
    unsigned*    __restrict__ annb,      // uint[N*64]
    const int*   __restrict__ gcnt,
    const v4i*   __restrict__ elist,
    int* __restrict__ cursor, v2i* __restrict__ pairs,
    int* __restrict__ ovfcnt, v4i* __restrict__ ovf,
    const int* __restrict__ ovf2cnt, const v4i* __restrict__ ovf2)
{
    if (blockIdx.x < B_BLOCKS) {
        int p = blockIdx.x & 7;            // XCD id under round-robin heuristic
        int k = blockIdx.x >> 3;           // [0, B_GROUP)
        int tid = threadIdx.x;

        int cnt = gcnt[p * CSTR];
        cnt = cnt > BUCK_CAP ? BUCK_CAP : cnt;

        for (int i = k * 256 + tid; i < cnt; i += B_GROUP * 256) {
            v4i e = __builtin_nontemporal_load(elist + ((size_t)p * BUCK_CAP + i));
            scatter_to_row(e.x, e.y, __int_as_float(e.z), cursor, pairs, ovfcnt, ovf);
        }

        // partition-overflow edges (expected 0): one block handles them all
        if (p == 0 && k == 0) {
            int n = *ovf2cnt;
            n = n > OVF2_CAP ? OVF2_CAP : n;
            for (int i = tid; i < n; i += 256) {
                v4i e = ovf2[i];
                scatter_to_row(e.x, e.y, __int_as_float(e.z), cursor, pairs, ovfcnt, ovf);
            }
        }
    } else {
        // fp32 -> bf16 (RNE), 8 floats / thread, 16B store.
        int t = (blockIdx.x - B_BLOCKS) * 256 + threadIdx.x;
        v4f f0 = __builtin_nontemporal_load(reinterpret_cast<const v4f*>(ann) + 2 * t);
        v4f f1 = __builtin_nontemporal_load(reinterpret_cast<const v4f*>(ann) + 2 * t + 1);
        v4u o;
        o.x = f2b_rne(f0.x) | (f2b_rne(f0.y) << 16);
        o.y = f2b_rne(f0.z) | (f2b_rne(f0.w) << 16);
        o.z = f2b_rne(f1.x) | (f2b_rne(f1.y) << 16);
        o.w = f2b_rne(f1.z) | (f2b_rne(f1.w) << 16);
        reinterpret_cast<v4u*>(annb)[t] = o;       // re-read by pull: cacheable
    }
}

// Stage C: pull, round-11 exact (8-deep, XCD-swizzled, VGPR-lean).
__global__ __launch_bounds__(256) void pull_kernel(
    const unsigned* __restrict__ annb,   // uint[N*64]
    const int*      __restrict__ cursor,
    const v2i*      __restrict__ pairs,
    const int*      __restrict__ ovfcnt,
    const v4i*      __restrict__ ovf,
    float*          __restrict__ out)
{
    int B = blockIdx.x;                            // [0, 10000)
    int L = (B & 7) * 1250 + (B >> 3);             // bijective row-block swizzle
    int r    = L * 4 + (threadIdx.x >> 6);
    int lane = threadIdx.x & 63;

    int cntr = cursor[r * CSTR];
    int cnt  = cntr > CAP ? CAP : cntr;

    int2 pr = make_int2(0, 0);                     // col 0, val 0.0f
    if (lane < cnt) {
        v2i p = pairs[r * CAP + lane];             // cacheable: XCD-L2 hit
        pr.x = p.x;
        pr.y = p.y;
    }

    float2 acc = make_float2(0.f, 0.f);
    int nb = (cnt + 7) & ~7;
    for (int j = 0; j < nb; j += 8) {
        #pragma unroll
        for (int k = 0; k < 8; k++) {
            int      c = __shfl(pr.x, j + k, 64);
            float    v = __int_as_float(__shfl(pr.y, j + k, 64));
            unsigned p = annb[c * (D_FEAT / 2) + lane];
            acc.x += v * __uint_as_float(p << 16);
            acc.y += v * __uint_as_float(p & 0xffff0000u);
        }
    }

    if (cntr > CAP) {                              // ~6 rows expected; tiny scan
        int n = *ovfcnt;
        n = n > OVF_CAP ? OVF_CAP : n;
        for (int i = 0; i < n; i++) {
            v4i e = ovf[i];                        // wave-uniform broadcast load
            if (e.x == r) {
                unsigned p = annb[e.y * (D_FEAT / 2) + lane];
                float    v = __int_as_float(e.z);
                acc.x += v * __uint_as_float(p << 16);
                acc.y += v * __uint_as_float(p & 0xffff0000u);
            }
        }
    }

    v2f o;
    o.x = acc.x;
    o.y = acc.y;
    __builtin_nontemporal_store(
        o, reinterpret_cast<v2f*>(out) + ((size_t)r * (D_FEAT / 2) + lane));
}

// ---- fallback (ws too small) ----
__global__ __launch_bounds__(256) void spmm_scatter_kernel(
    const int*   __restrict__ rows,
    const int*   __restrict__ cols,
    const float* __restrict__ vals,
    const float* __restrict__ ann,
    float*       __restrict__ out)
{
    int t = blockIdx.x * blockDim.x + threadIdx.x;
    int e = t >> 5;
    if (e >= N_EDGES) return;
    int lane = t & 31;
    int   r = rows[e];
    int   c = cols[e];
    float v = vals[e];
    float4 a = reinterpret_cast<const float4*>(ann)[(size_t)c * (D_FEAT / 4) + lane];
    float* o = out + (size_t)r * D_FEAT + lane * 4;
    unsafeAtomicAdd(o + 0, v * a.x);
    unsafeAtomicAdd(o + 1, v * a.y);
    unsafeAtomicAdd(o + 2, v * a.z);
    unsafeAtomicAdd(o + 3, v * a.w);
}

extern "C" void kernel_launch(void* const* d_in, const int* in_sizes, int n_in,
                              void* d_out, int out_size, void* d_ws, size_t ws_size,
                              hipStream_t stream) {
    const int*   rows = (const int*)  d_in[0];
    const int*   cols = (const int*)  d_in[1];
    const float* vals = (const float*)d_in[2];
    const float* ann  = (const float*)d_in[3];
    float*       out  = (float*)      d_out;

    if (ws_size < WS_NEEDED) {
        hipMemsetAsync(out, 0, (size_t)out_size * sizeof(float), stream);
        const long long total_threads = (long long)N_EDGES * 32;
        spmm_scatter_kernel<<<dim3((unsigned)((total_threads + 255) / 256)),
                              dim3(256), 0, stream>>>(rows, cols, vals, ann, out);
        return;
    }

    char*     ws      = (char*)d_ws;
    int*      cursor  = (int*)     (ws + WS_CURSOR);
    int*      ovfcnt  = (int*)     (ws + WS_OVFCNT);
    int*      gcnt    = (int*)     (ws + WS_GCNT);
    int*      ovf2cnt = (int*)     (ws + WS_OVF2CNT);
    v4i*      ovf     = (v4i*)     (ws + WS_OVF);
    v4i*      ovf2    = (v4i*)     (ws + WS_OVF2);
    unsigned* annb    = (unsigned*)(ws + WS_ANNB);
    v4i*      elist   = (v4i*)     (ws + WS_ELIST);
    v2i*      pairs   = (v2i*)     (ws + WS_PAIRS);

    hipMemsetAsync(cursor, 0, WS_ZERO, stream);    // cursor+ovfcnt+gcnt+ovf2cnt

    partition_kernel<<<dim3(A_BLOCKS), dim3(256), 0, stream>>>(
        rows, cols, vals, gcnt, elist, ovf2cnt, ovf2);

    build_kernel<<<dim3(B_BLOCKS + CONV_BLOCKS), dim3(256), 0, stream>>>(
        ann, annb, gcnt, elist, cursor, pairs, ovfcnt, ovf, ovf2cnt, ovf2);

    const long long pull_threads = (long long)N_NODES * 64;
    pull_kernel<<<dim3((unsigned)((pull_threads + 255) / 256)), dim3(256), 0, stream>>>(
        annb, cursor, pairs, ovfcnt, ovf, out);
}

// Round 11
// 135.284 us; speedup vs baseline: 1.1980x; 1.1980x over previous
//
#include <hip/hip_runtime.h>

// SpMM (COO): out[rows[e], :] += vals[e] * annotations[cols[e], :]
// N=40000 nodes, E=640000 edges, D=128 feats, fp32 in/out.
//
// Round 15: RESTORE round-11 exact (best measured: 136.0 us).
//   Round-10's pre-partition decomposition was null-to-negative (162 us):
//   the 640k cursor-atomic coherence chain is the wall, and adding a
//   binning stage around it only adds traffic. Final structure:
//   - build: XCD-partitioned edge scan (blockIdx&7 rides the round-robin
//     XCD placement; 8x duplicated L3-hot edge reads), cursor atomic +
//     pairs store against per-XCD L2-resident slices; convert (fp32->bf16
//     annb) fused behind as trailing blocks.
//   - pull: wave-per-row, 8-deep shfl-broadcast gather loop, VGPR-lean,
//     XCD-swizzled row blocks, NT out stores.
//   Ledger at floor: fill 46 (harness) + build 45 + pull 38 + memset 2.5.
//   Both hot kernels pinned at ~28G random-line-ops/s (coherence/latency
//   ceiling, not BW): 5 scatter attacks and 4 pull attacks all <=3 us.

constexpr int N_NODES = 40000;
constexpr int N_EDGES = 640000;
constexpr int D_FEAT  = 128;
constexpr int CAP     = 32;       // slots per row; deg>CAP spills to overflow
constexpr int OVF_CAP = 16384;
constexpr int CSTR    = 16;       // cursor stride (ints): 1 counter per 64B line

constexpr int NXCD      = 8;
constexpr int PART_ROWS = N_NODES / NXCD;          // 5000 rows per partition
constexpr int EPT       = 10;                      // edges per thread (scan)
constexpr int CHUNK     = 256 * EPT;               // 2560 edges per block-scan
constexpr int NCHUNK    = N_EDGES / CHUNK;         // 250
constexpr int SCAT_BLOCKS = NCHUNK * NXCD;         // 2000
constexpr int CONV_BLOCKS = (N_NODES * D_FEAT / 8) / 256;  // 2500

// ---- workspace layout (bytes) ----
constexpr size_t WS_CURSOR = 0;                         // int[N*CSTR] = 2,560,000
constexpr size_t WS_OVFCNT = 2560000;                   // int
constexpr size_t WS_OVF    = 2560256;                   // int4[OVF_CAP] = 262,144
constexpr size_t WS_ANNB   = 2822400;                   // bf16[N*D] as uint[N*64]
constexpr size_t WS_PAIRS  = 13062400;                  // int2[N*CAP] = 10,240,000
constexpr size_t WS_ZERO   = 2560256;                   // bytes to memset (cursor+ovfcnt)
constexpr size_t WS_NEEDED = 23302400;

typedef int      v2i __attribute__((ext_vector_type(2)));
typedef float    v2f __attribute__((ext_vector_type(2)));
typedef float    v4f __attribute__((ext_vector_type(4)));
typedef unsigned v4u __attribute__((ext_vector_type(4)));

__device__ __forceinline__ unsigned f2b_rne(float f) {
    unsigned b = __float_as_uint(f);
    return (b + 0x7fffu + ((b >> 16) & 1u)) >> 16;
}

// Fused partition-filtered scatter + convert.
__global__ __launch_bounds__(256) void build_kernel(
    const int*   __restrict__ rows,
    const int*   __restrict__ cols,
    const float* __restrict__ vals,
    const float* __restrict__ ann,
    unsigned*    __restrict__ annb,      // uint[N*64]
    int* __restrict__ cursor, v2i* __restrict__ pairs,
    int* __restrict__ ovfcnt, int4* __restrict__ ovf)
{
    if (blockIdx.x < SCAT_BLOCKS) {
        int p     = blockIdx.x & 7;        // XCD id under round-robin placement
        int chunk = blockIdx.x >> 3;       // [0, 250)
        int e0    = chunk * CHUNK + threadIdx.x;

        int   r[EPT], c[EPT];
        float v[EPT];
        #pragma unroll
        for (int i = 0; i < EPT; i++) {    // static idx -> VGPRs; full MLP
            int e = e0 + i * 256;          // coalesced per i
            r[i] = __builtin_nontemporal_load(rows + e);
            c[i] = __builtin_nontemporal_load(cols + e);
            v[i] = __builtin_nontemporal_load(vals + e);
        }
        #pragma unroll
        for (int i = 0; i < EPT; i++) {
            if (r[i] / PART_ROWS != p) continue;   // not our partition
            int slot = atomicAdd(&cursor[r[i] * CSTR], 1);   // XCD-local line
            if (slot < CAP) {
                v2i q;
                q.x = c[i];
                q.y = __float_as_int(v[i]);
                pairs[r[i] * CAP + slot] = q;      // XCD-local: combines in L2
            } else {
                int o = atomicAdd(ovfcnt, 1);
                if (o < OVF_CAP)
                    ovf[o] = make_int4(r[i], c[i], __float_as_int(v[i]), 0);
            }
        }
    } else {
        // fp32 -> bf16 (RNE), 8 floats / thread, 16B store.
        int t = (blockIdx.x - SCAT_BLOCKS) * 256 + threadIdx.x;
        v4f f0 = __builtin_nontemporal_load(reinterpret_cast<const v4f*>(ann) + 2 * t);
        v4f f1 = __builtin_nontemporal_load(reinterpret_cast<const v4f*>(ann) + 2 * t + 1);
        v4u o;
        o.x = f2b_rne(f0.x) | (f2b_rne(f0.y) << 16);
        o.y = f2b_rne(f0.z) | (f2b_rne(f0.w) << 16);
        o.z = f2b_rne(f1.x) | (f2b_rne(f1.y) << 16);
        o.w = f2b_rne(f1.z) | (f2b_rne(f1.w) << 16);
        reinterpret_cast<v4u*>(annb)[t] = o;       // re-read by pull: cacheable
    }
}

// One wave (64 lanes) per row; lane owns feats [2l, 2l+1] (one uint = 2 bf16).
// Block swizzle keeps each block's 4 rows in the partition matching its XCD
// (B&7), so cursor/pairs reads hit the L2 that build just wrote.
__global__ __launch_bounds__(256) void pull_kernel(
    const unsigned* __restrict__ annb,   // uint[N*64]
    const int*      __restrict__ cursor,
    const v2i*      __restrict__ pairs,
    const int*      __restrict__ ovfcnt,
    const int4*     __restrict__ ovf,
    float*          __restrict__ out)
{
    int B = blockIdx.x;                            // [0, 10000)
    int L = (B & 7) * 1250 + (B >> 3);             // bijective row-block swizzle
    int r    = L * 4 + (threadIdx.x >> 6);
    int lane = threadIdx.x & 63;

    int cntr = cursor[r * CSTR];
    int cnt  = cntr > CAP ? CAP : cntr;

    int2 pr = make_int2(0, 0);                     // col 0, val 0.0f
    if (lane < cnt) {
        v2i p = pairs[r * CAP + lane];             // cacheable: XCD-L2 hit
        pr.x = p.x;
        pr.y = p.y;
    }

    float2 acc = make_float2(0.f, 0.f);
    int nb = (cnt + 7) & ~7;
    for (int j = 0; j < nb; j += 8) {
        #pragma unroll
        for (int k = 0; k < 8; k++) {
            int      c = __shfl(pr.x, j + k, 64);
            float    v = __int_as_float(__shfl(pr.y, j + k, 64));
            unsigned p = annb[c * (D_FEAT / 2) + lane];
            acc.x += v * __uint_as_float(p << 16);
            acc.y += v * __uint_as_float(p & 0xffff0000u);
        }
    }

    if (cntr > CAP) {                              // ~6 rows expected; tiny scan
        int n = *ovfcnt;
        n = n > OVF_CAP ? OVF_CAP : n;
        for (int i = 0; i < n; i++) {
            int4 e = ovf[i];                       // wave-uniform broadcast load
            if (e.x == r) {
                unsigned p = annb[e.y * (D_FEAT / 2) + lane];
                float    v = __int_as_float(e.z);
                acc.x += v * __uint_as_float(p << 16);
                acc.y += v * __uint_as_float(p & 0xffff0000u);
            }
        }
    }

    v2f o;
    o.x = acc.x;
    o.y = acc.y;
    __builtin_nontemporal_store(
        o, reinterpret_cast<v2f*>(out) + ((size_t)r * (D_FEAT / 2) + lane));
}

// ---- fallback (ws too small) ----
__global__ __launch_bounds__(256) void spmm_scatter_kernel(
    const int*   __restrict__ rows,
    const int*   __restrict__ cols,
    const float* __restrict__ vals,
    const float* __restrict__ ann,
    float*       __restrict__ out)
{
    int t = blockIdx.x * blockDim.x + threadIdx.x;
    int e = t >> 5;
    if (e >= N_EDGES) return;
    int lane = t & 31;
    int   r = rows[e];
    int   c = cols[e];
    float v = vals[e];
    float4 a = reinterpret_cast<const float4*>(ann)[(size_t)c * (D_FEAT / 4) + lane];
    float* o = out + (size_t)r * D_FEAT + lane * 4;
    unsafeAtomicAdd(o + 0, v * a.x);
    unsafeAtomicAdd(o + 1, v * a.y);
    unsafeAtomicAdd(o + 2, v * a.z);
    unsafeAtomicAdd(o + 3, v * a.w);
}

extern "C" void kernel_launch(void* const* d_in, const int* in_sizes, int n_in,
                              void* d_out, int out_size, void* d_ws, size_t ws_size,
                              hipStream_t stream) {
    const int*   rows = (const int*)  d_in[0];
    const int*   cols = (const int*)  d_in[1];
    const float* vals = (const float*)d_in[2];
    const float* ann  = (const float*)d_in[3];
    float*       out  = (float*)      d_out;

    if (ws_size < WS_NEEDED) {
        hipMemsetAsync(out, 0, (size_t)out_size * sizeof(float), stream);
        const long long total_threads = (long long)N_EDGES * 32;
        spmm_scatter_kernel<<<dim3((unsigned)((total_threads + 255) / 256)),
                              dim3(256), 0, stream>>>(rows, cols, vals, ann, out);
        return;
    }

    char*     ws     = (char*)d_ws;
    int*      cursor = (int*)     (ws + WS_CURSOR);
    int*      ovfcnt = (int*)     (ws + WS_OVFCNT);
    int4*     ovf    = (int4*)    (ws + WS_OVF);
    unsigned* annb   = (unsigned*)(ws + WS_ANNB);
    v2i*      pairs  = (v2i*)     (ws + WS_PAIRS);

    hipMemsetAsync(cursor, 0, WS_ZERO, stream);    // cursor + ovfcnt, DMA fill

    build_kernel<<<dim3(SCAT_BLOCKS + CONV_BLOCKS), dim3(256), 0, stream>>>(
        rows, cols, vals, ann, annb, cursor, pairs, ovfcnt, ovf);

    const long long pull_threads = (long long)N_NODES * 64;
    pull_kernel<<<dim3((unsigned)((pull_threads + 255) / 256)), dim3(256), 0, stream>>>(
        annb, cursor, pairs, ovfcnt, ovf, out);
}